// Round 5
// baseline (1279.245 us; speedup 1.0000x reference)
//
#include <hip/hip_runtime.h>
#include <hip/hip_fp16.h>

// MINE estimator, dropout analytically marginalized:
//   mean(z1)  -> no-dropout forward (exact expectation)
//   E[exp(z2)] = exp(b3) * prod_j (0.5 + 0.5*exp(2*a_j)),  a_j = w3_j*relu(h2_j)
//   permutation -> 20 fixed cyclic shifts (unbiased pairing estimator)
// R9: break the phase convoy. R7 accounting: MFMA pipe needs 3880 CU-cy per
//   block-pass but blocks complete one per 12300 cy (MfmaUtil 31.5%): the two
//   per-pass barriers convoy all waves into stage->MFMA->epilogue lockstep,
//   and the 3 co-resident blocks convoy too (identical phase lengths).
//   - fc23 staging replaced by global_load_lds DMA of P-tile and Q-tile into
//     SEPARATE LDS buffers (no VGPR round trip, no stage VALU, no stage
//     barrier pair). relu(P+Q) computed in the kt-loop from two ds_reads.
//   - swizzled slots preserved by inverse-permuting the GLOBAL source addr
//     (slot map is an involution); reads unchanged from R7 -> conflict-free.
//   - ONE barrier after DMA (each wave vmcnt(0)s its own loads); kt-loop and
//     epilogue barrier-free -> waves/blocks drift and hide each other's
//     stalls. Tiny end barriers for the 1KB part exchange (aliases Pt).
//   - bias fold: fc1 writes P[.][300]=0.5, Q[.][300]=0.5 -> relu(P+Q)=1.
//   - LDS 40+40 KB = 81920 exactly -> 2 blocks/CU; regs ~210 < 256 cap of
//     (256,2) -> 2 waves/SIMD, no spill (WRITE_SIZE canary ~1.3e3 KB).

#define N_SAMP  131072
#define NMASK   (N_SAMP - 1)
#define HH      300
#define HPAD    320
#define DD      256
#define KPASS   20
#define PSTRIDE 320

#define OFF_S    ((size_t)0)
#define OFF_B1P  ((size_t)1024)
#define OFF_B2P  ((size_t)2304)
#define OFF_W3P  ((size_t)3584)
#define OFF_C2   ((size_t)4864)
#define OFF_W1B  ((size_t)8192)                       // [20 nt][8 kt][64 lane][8] f16
#define OFF_W2B  (OFF_W1B + (size_t)163840)           // [4 nq][50 ktn][64 lane][8] f16
#define OFF_P    (OFF_W2B + (size_t)204800)
#define OFF_Q    (OFF_P + (size_t)N_SAMP*PSTRIDE*2)

typedef _Float16 f16x8 __attribute__((ext_vector_type(8)));
typedef float    fx4   __attribute__((ext_vector_type(4)));

__device__ __forceinline__ void gload_lds16(const void* g, void* l)
{
    __builtin_amdgcn_global_load_lds(
        (const __attribute__((address_space(1))) void*)g,
        (__attribute__((address_space(3))) void*)l, 16, 0, 0);
}

__global__ void prep_kernel(const float* __restrict__ W1, const float* __restrict__ b1,
                            const float* __restrict__ W2, const float* __restrict__ b2,
                            const float* __restrict__ W3, char* __restrict__ ws)
{
    double* S     = (double*)(ws + OFF_S);
    float* b1p    = (float*)(ws + OFF_B1P);
    float* b2p    = (float*)(ws + OFF_B2P);
    float* w3p    = (float*)(ws + OFF_W3P);
    float* c2p    = (float*)(ws + OFF_C2);
    _Float16* w1b = (_Float16*)(ws + OFF_W1B);
    _Float16* w2b = (_Float16*)(ws + OFF_W2B);
    int tid = blockIdx.x * blockDim.x + threadIdx.x;
    int nth = gridDim.x * blockDim.x;
    if (tid <= KPASS) S[tid] = 0.0;
    for (int i = tid; i < HPAD; i += nth) {
        b1p[i] = (i < HH) ? b1[i] : ((i == HH) ? 0.5f : 0.f);  // col 300: bias half
        b2p[i] = (i < HH) ? b2[i] : 0.f;
        w3p[i] = (i < HH) ? W3[i] : 0.f;
        c2p[i] = (i < HH) ? 2.8853900817779268f * W3[i] : 0.f;  // 2*log2(e)*w3
    }
    // w1b: frag (nt,kt): value = W1[n][k], n = nt*16+tx, k = kt*32+quad*8+j (K=256)
    for (int i = tid; i < 20 * 8 * 64 * 8; i += nth) {
        const int j = i & 7, lane = (i >> 3) & 63, rem = i >> 9;
        const int kt = rem & 7, nt = rem >> 3;
        const int n = nt * 16 + (lane & 15);
        const int k = kt * 32 + (lane >> 4) * 8 + j;
        w1b[i] = (n < HH) ? (_Float16)W1[n * DD + k] : (_Float16)0.f;
    }
    // w2b kt-major: [nq][kt*5+n][lane][8]; value = W2[nt*16+tx][kt*32+quad*8+j],
    // nt = nq*5+n; row k==300 carries b2 (bias fold)
    for (int i = tid; i < 4 * 50 * 64 * 8; i += nth) {
        const int j = i & 7, lane = (i >> 3) & 63, rem = i >> 9;   // rem 0..199
        const int nq = rem / 50, r2 = rem - nq * 50;
        const int kt = r2 / 5,  nn = r2 - kt * 5;
        const int nt = nq * 5 + nn;
        const int n = nt * 16 + (lane & 15);
        const int k = kt * 32 + (lane >> 4) * 8 + j;
        float v = 0.f;
        if (n < HH) {
            if (k < HH)       v = W2[n * HH + k];
            else if (k == HH) v = b2[n];
        }
        w2b[i] = (_Float16)v;
    }
}

// fc1 on MFMA: gather x rows -> fp16 A-frags in LDS; P = u*W1a^T + b1 (kt 0..3),
// Q = v*W1b^T (kt 4..7). Epilogue transposes through LDS for coalesced stores.
// Col 300 of BOTH P and Q gets 0.5 so fc23's relu(P+Q) sees 1.0 (b2 fold).
__global__ __launch_bounds__(256, 2)
void fc1_kernel(const float* __restrict__ x, const int* __restrict__ ind,
                char* __restrict__ ws)
{
    const _Float16* w1b = (const _Float16*)(ws + OFF_W1B);
    const float* b1p    = (const float*)(ws + OFF_B1P);
    const int i0 = blockIdx.x * 128;

    __shared__ __align__(16) char lds[65536];   // At [8 kt][8 mt][64 slot][8] f16
    _Float16* At  = (_Float16*)lds;
    _Float16* buf = (_Float16*)lds;

    const int t    = threadIdx.x;
    const int lane = t & 63, w = t >> 6;
    const int tx   = lane & 15, quad = lane >> 4;
    const int colw = w * 80;

    {
        const int m = t >> 1, c = t & 1;
        const int mt = m >> 4, ml = m & 15;
        const int r = ind[i0 + m];
        const float* xr = x + (size_t)r * DD;
        #pragma unroll
        for (int i = 0; i < 16; ++i) {
            const int ch = 2 * i + c;
            const int kt = ch >> 2, qd = ch & 3;
            const float4 f0 = *(const float4*)(xr + ch * 8);
            const float4 f1 = *(const float4*)(xr + ch * 8 + 4);
            f16x8 h;
            h[0] = (_Float16)f0.x; h[1] = (_Float16)f0.y;
            h[2] = (_Float16)f0.z; h[3] = (_Float16)f0.w;
            h[4] = (_Float16)f1.x; h[5] = (_Float16)f1.y;
            h[6] = (_Float16)f1.z; h[7] = (_Float16)f1.w;
            *(f16x8*)(At + ((size_t)(kt * 8 + mt) * 64 + ml * 4 + qd) * 8) = h;
        }
    }
    __syncthreads();

    #pragma unroll
    for (int ph = 0; ph < 2; ++ph) {
        fx4 acc[8][5] = {};
        #pragma unroll
        for (int kt = 0; kt < 4; ++kt) {
            const int ktg = ph * 4 + kt;
            f16x8 bf[5];
            #pragma unroll
            for (int n = 0; n < 5; ++n)
                bf[n] = *(const f16x8*)(w1b + ((size_t)((w * 5 + n) * 8 + ktg) * 64 + lane) * 8);
            #pragma unroll
            for (int mh = 0; mh < 2; ++mh) {
                f16x8 af[4];
                #pragma unroll
                for (int mi = 0; mi < 4; ++mi)
                    af[mi] = *(const f16x8*)(At + ((size_t)(ktg * 8 + mh * 4 + mi) * 64 + tx * 4 + quad) * 8);
                #pragma unroll
                for (int mi = 0; mi < 4; ++mi)
                    #pragma unroll
                    for (int n = 0; n < 5; ++n)
                        acc[mh * 4 + mi][n] =
                            __builtin_amdgcn_mfma_f32_16x16x32_f16(af[mi], bf[n], acc[mh * 4 + mi][n], 0, 0, 0);
            }
        }
        _Float16* out = (_Float16*)(ws + (ph ? OFF_Q : OFF_P));
        #pragma unroll
        for (int g = 0; g < 4; ++g) {
            __syncthreads();
            #pragma unroll
            for (int mi = 0; mi < 2; ++mi) {
                const int mt = g * 2 + mi;
                #pragma unroll
                for (int n = 0; n < 5; ++n) {
                    const int col = colw + n * 16 + tx;
                    const float bb = (ph == 0) ? b1p[col]
                                               : ((col == HH) ? 0.5f : 0.f);
                    #pragma unroll
                    for (int r = 0; r < 4; ++r) {
                        const int row32 = mi * 16 + quad * 4 + r;
                        buf[row32 * 328 + col] = (_Float16)(acc[mt][n][r] + bb);
                    }
                }
            }
            __syncthreads();
            #pragma unroll
            for (int s5 = 0; s5 < 5; ++s5) {
                const int idx = t + s5 * 256;
                const int rr = idx / 40, cc = idx - rr * 40;
                *(uint4*)(out + (size_t)(i0 + g * 32 + rr) * PSTRIDE + cc * 8) =
                    *(const uint4*)(buf + rr * 328 + cc * 8);
            }
        }
        __syncthreads();
    }
}

// fc2+fc3: h1 = relu(P_i + Q_{(i+shift)&mask}); h2 = h1*W2b^T; epilogue in
// exp2/log2 domain. R9: grid (2048,21); 256 threads / 4 waves, each wave all
// 64 rows x its 80-col quadrant (acc[4][5] AGPR). P/Q DMA'd into separate
// swizzled LDS tiles via global_load_lds; relu(P+Q) inline in the kt-loop.
// One barrier after DMA; kt-loop + epilogue barrier-free.
__global__ __launch_bounds__(256, 2)
void fc23_kernel(char* __restrict__ ws)
{
    const _Float16* w2b = (const _Float16*)(ws + OFF_W2B);
    const float* w3p = (const float*)(ws + OFF_W3P);
    const float* c2p = (const float*)(ws + OFF_C2);
    const _Float16* P = (const _Float16*)(ws + OFF_P);
    const _Float16* Q = (const _Float16*)(ws + OFF_Q);
    double* S = (double*)(ws + OFF_S);

    const int p  = blockIdx.y;
    const int i0 = blockIdx.x * 64;
    const unsigned shift = (p == 0) ? 0u : (((unsigned)p * 2654435761u) & NMASK);

    __shared__ __align__(16) char lds[81920];
    _Float16* Pt = (_Float16*)lds;               // [4 mt][10 kt][64 slot^swz][8]
    _Float16* Qt = (_Float16*)(lds + 40960);     // same layout
    float* part  = (float*)lds;                  // [64 rows][4 waves], aliases Pt

    const int t    = threadIdx.x;
    const int lane = t & 63, w = t >> 6;         // w = nq quadrant AND mt for DMA
    const int tx   = lane & 15, quad = lane >> 4;
    const int colw = w * 80;

    // DMA staging: wave w stages mt=w of both tiles. Lane l writes LDS slot l;
    // inverse-swizzle g = l ^ ((l>>3)&3) (involution) picks the global data
    // (ml = g>>2, cq = g&3) so that swizzled READS (rs below) are conflict-free.
    {
        const int g = lane ^ ((lane >> 3) & 3);
        const int prow = i0 + w * 16 + (g >> 2);
        const unsigned qrow = ((unsigned)prow + shift) & NMASK;
        const char* psrc = (const char*)(P + (size_t)prow * PSTRIDE) + (g & 3) * 16;
        const char* qsrc = (const char*)(Q + (size_t)qrow * PSTRIDE) + (g & 3) * 16;
        char* pdst = (char*)Pt + w * 10240;
        char* qdst = (char*)Qt + w * 10240;
        #pragma unroll
        for (int kt = 0; kt < 10; ++kt) {
            gload_lds16(psrc + kt * 64, pdst + kt * 1024);
            gload_lds16(qsrc + kt * 64, qdst + kt * 1024);
        }
    }

    // B-frag stream base (kt-major): frag (kt,n) at +(kt*5+n)*512 f16
    const _Float16* wb = w2b + (size_t)(w * 50) * 512 + (size_t)lane * 8;
    f16x8 bA[5], bB[5];
    #pragma unroll
    for (int n = 0; n < 5; ++n) bA[n] = *(const f16x8*)(wb + (size_t)n * 512);

    asm volatile("s_waitcnt vmcnt(0)" ::: "memory");   // own DMAs (and bA) done
    __syncthreads();                                   // all waves' DMAs visible

    int rs = tx * 4 + quad;  rs ^= (rs >> 3) & 3;      // swizzled read slot

    fx4 acc[4][5] = {};
    #pragma unroll
    for (int kt = 0; kt < 10; ++kt) {
        f16x8* bc = (kt & 1) ? bB : bA;
        f16x8* bn = (kt & 1) ? bA : bB;
        if (kt < 9) {
            #pragma unroll
            for (int n = 0; n < 5; ++n)
                bn[n] = *(const f16x8*)(wb + (size_t)((kt + 1) * 5 + n) * 512);
        }
        f16x8 af[4];
        #pragma unroll
        for (int mi = 0; mi < 4; ++mi) {
            const size_t o = ((size_t)(mi * 10 + kt) * 64 + rs) * 8;
            f16x8 ap = *(const f16x8*)(Pt + o);
            f16x8 aq = *(const f16x8*)(Qt + o);
            f16x8 sv = ap + aq;
            af[mi] = __builtin_elementwise_max(sv, (f16x8)(_Float16)0);
        }
        #pragma unroll
        for (int mi = 0; mi < 4; ++mi)
            #pragma unroll
            for (int n = 0; n < 5; ++n)
                acc[mi][n] =
                    __builtin_amdgcn_mfma_f32_16x16x32_f16(af[mi], bc[n], acc[mi][n], 0, 0, 0);
    }

    // epilogue: fc3 dot (p==0) or marginalized-dropout product (p>0),
    // in exp2/log2 domain; results held in regs until the part exchange
    float w3v[5], c2v[5];
    #pragma unroll
    for (int n = 0; n < 5; ++n) {
        w3v[n] = w3p[colw + n * 16 + tx];
        c2v[n] = c2p[colw + n * 16 + tx];
    }
    float psv[4][4];
    #pragma unroll
    for (int mi = 0; mi < 4; ++mi) {
        float ps[4];
        if (p == 0) {
            ps[0] = ps[1] = ps[2] = ps[3] = 0.f;
            #pragma unroll
            for (int n = 0; n < 5; ++n)
                #pragma unroll
                for (int r = 0; r < 4; ++r)
                    ps[r] = fmaf(w3v[n], fmaxf(acc[mi][n][r], 0.f), ps[r]);
        } else {
            float prd[4] = {1.f, 1.f, 1.f, 1.f};
            #pragma unroll
            for (int n = 0; n < 5; ++n)
                #pragma unroll
                for (int r = 0; r < 4; ++r) {
                    const float hr = fmaxf(acc[mi][n][r], 0.f);
                    const float u  = __builtin_amdgcn_exp2f(c2v[n] * hr);  // e^{2a}
                    prd[r] *= fmaf(0.5f, u, 0.5f);
                }
            #pragma unroll
            for (int r = 0; r < 4; ++r)
                ps[r] = __builtin_amdgcn_logf(prd[r]);   // v_log_f32 = log2
        }
        #pragma unroll
        for (int r = 0; r < 4; ++r) {
            float v = ps[r];
            v += __shfl_xor(v, 1); v += __shfl_xor(v, 2);
            v += __shfl_xor(v, 4); v += __shfl_xor(v, 8);
            psv[mi][r] = v;
        }
    }
    __syncthreads();   // all Pt/Qt reads done -> part may alias Pt

    if (tx == 0) {
        #pragma unroll
        for (int mi = 0; mi < 4; ++mi)
            #pragma unroll
            for (int r = 0; r < 4; ++r)
                part[(mi * 16 + quad * 4 + r) * 4 + w] = psv[mi][r];
    }
    __syncthreads();

    if (t < 64) {      // wave 0: fold 4 nq partials, reduce 64 rows
        const float4 pv = *(const float4*)(part + t * 4);
        const float s = pv.x + pv.y + pv.z + pv.w;
        float tot = (p == 0) ? s : __builtin_amdgcn_exp2f(s);
        tot += __shfl_xor(tot, 1);  tot += __shfl_xor(tot, 2);
        tot += __shfl_xor(tot, 4);  tot += __shfl_xor(tot, 8);
        tot += __shfl_xor(tot, 16); tot += __shfl_xor(tot, 32);
        if (t == 0) atomicAdd(&S[p], (double)tot);
    }
}

__global__ void fin_kernel(char* __restrict__ ws, float* __restrict__ out)
{
    if (threadIdx.x == 0 && blockIdx.x == 0) {
        const double* S = (const double*)(ws + OFF_S);
        double m1 = S[0] / (double)N_SAMP;
        double a = 0.0;
        for (int p = 1; p <= KPASS; ++p) a += log(S[p] / (double)N_SAMP);
        out[0] = (float)(m1 - a / (double)KPASS);
    }
}

extern "C" void kernel_launch(void* const* d_in, const int* in_sizes, int n_in,
                              void* d_out, int out_size, void* d_ws, size_t ws_size,
                              hipStream_t stream)
{
    const float* x  = (const float*)d_in[0];
    const int* ind  = (const int*)d_in[1];
    const float* W1 = (const float*)d_in[2];
    const float* b1 = (const float*)d_in[3];
    const float* W2 = (const float*)d_in[4];
    const float* b2 = (const float*)d_in[5];
    const float* W3 = (const float*)d_in[6];
    char* ws = (char*)d_ws;

    hipLaunchKernelGGL(prep_kernel, dim3(512), dim3(256), 0, stream, W1, b1, W2, b2, W3, ws);
    hipLaunchKernelGGL(fc1_kernel, dim3(N_SAMP / 128), dim3(256), 0, stream, x, ind, ws);
    hipLaunchKernelGGL(fc23_kernel, dim3(N_SAMP / 64, KPASS + 1), dim3(256), 0, stream, ws);
    hipLaunchKernelGGL(fin_kernel, dim3(1), dim3(64), 0, stream, ws, (float*)d_out);
}

// Round 6
// 1238.166 us; speedup vs baseline: 1.0332x; 1.0332x over previous
//
#include <hip/hip_runtime.h>
#include <hip/hip_fp16.h>

// MINE estimator, dropout analytically marginalized:
//   mean(z1)  -> no-dropout forward (exact expectation)
//   E[exp(z2)] = exp(b3) * prod_j (0.5 + 0.5*exp(2*a_j)),  a_j = w3_j*relu(h2_j)
//   permutation -> 20 fixed cyclic shifts (unbiased pairing estimator)
// R10: TLP at constant ILP. R7 (818us) was LDS-capped at 3 blocks/CU (126KB),
//   pipes 70% combined (Mfma 31.5 + VALU 39) -- not enough waves to pack them.
//   R9 showed in-loop relu + 2-block occupancy is worse; R8 showed M=128 with
//   4 waves spills (acc[8][5] = 160 AGPR > cap).
//   - fc23: 512 threads / 8 waves, M=128/block; each wave keeps R7's exact
//     shape: acc[4][5] (80 AGPR), 20 MFMA/kt, own 80-col quadrant, 64 rows.
//     At = [8 mt][10 kt][64 slot^swz][8] f16 = exactly 81920 B -> 2 blocks/CU
//     = 16 waves/CU (~50%) since regs ~164 allow 4 waves/SIMD.
//   - w2b L2 traffic halves (1024x21 blocks); staging stays 4 threads/row
//     (R8's bank conflicts came from its 2-threads/row map).
//   - s_setprio(1) around the MFMA cluster (T5): 16 waves with stage/MFMA/
//     epilogue role diversity -> scheduler can favor MFMA-phase waves.
//   - part aliases At behind the post-MFMA barrier. Spill canary: WRITE_SIZE
//     must stay ~1.3e3 KB.

#define N_SAMP  131072
#define NMASK   (N_SAMP - 1)
#define HH      300
#define HPAD    320
#define DD      256
#define KPASS   20
#define PSTRIDE 320

#define OFF_S    ((size_t)0)
#define OFF_B1P  ((size_t)1024)
#define OFF_B2P  ((size_t)2304)
#define OFF_W3P  ((size_t)3584)
#define OFF_C2   ((size_t)4864)
#define OFF_W1B  ((size_t)8192)                       // [20 nt][8 kt][64 lane][8] f16
#define OFF_W2B  (OFF_W1B + (size_t)163840)           // [4 nq][50 ktn][64 lane][8] f16
#define OFF_P    (OFF_W2B + (size_t)204800)
#define OFF_Q    (OFF_P + (size_t)N_SAMP*PSTRIDE*2)

typedef _Float16 f16x8 __attribute__((ext_vector_type(8)));
typedef float    fx4   __attribute__((ext_vector_type(4)));

__global__ void prep_kernel(const float* __restrict__ W1, const float* __restrict__ b1,
                            const float* __restrict__ W2, const float* __restrict__ b2,
                            const float* __restrict__ W3, char* __restrict__ ws)
{
    double* S     = (double*)(ws + OFF_S);
    float* b1p    = (float*)(ws + OFF_B1P);
    float* b2p    = (float*)(ws + OFF_B2P);
    float* w3p    = (float*)(ws + OFF_W3P);
    float* c2p    = (float*)(ws + OFF_C2);
    _Float16* w1b = (_Float16*)(ws + OFF_W1B);
    _Float16* w2b = (_Float16*)(ws + OFF_W2B);
    int tid = blockIdx.x * blockDim.x + threadIdx.x;
    int nth = gridDim.x * blockDim.x;
    if (tid <= KPASS) S[tid] = 0.0;
    for (int i = tid; i < HPAD; i += nth) {
        b1p[i] = (i < HH) ? b1[i] : 0.f;
        b2p[i] = (i < HH) ? b2[i] : 0.f;
        w3p[i] = (i < HH) ? W3[i] : 0.f;
        c2p[i] = (i < HH) ? 2.8853900817779268f * W3[i] : 0.f;  // 2*log2(e)*w3
    }
    // w1b: frag (nt,kt): value = W1[n][k], n = nt*16+tx, k = kt*32+quad*8+j (K=256)
    for (int i = tid; i < 20 * 8 * 64 * 8; i += nth) {
        const int j = i & 7, lane = (i >> 3) & 63, rem = i >> 9;
        const int kt = rem & 7, nt = rem >> 3;
        const int n = nt * 16 + (lane & 15);
        const int k = kt * 32 + (lane >> 4) * 8 + j;
        w1b[i] = (n < HH) ? (_Float16)W1[n * DD + k] : (_Float16)0.f;
    }
    // w2b kt-major: [nq][kt*5+n][lane][8]; value = W2[nt*16+tx][kt*32+quad*8+j],
    // nt = nq*5+n; row k==300 carries b2 (bias fold)
    for (int i = tid; i < 4 * 50 * 64 * 8; i += nth) {
        const int j = i & 7, lane = (i >> 3) & 63, rem = i >> 9;   // rem 0..199
        const int nq = rem / 50, r2 = rem - nq * 50;
        const int kt = r2 / 5,  nn = r2 - kt * 5;
        const int nt = nq * 5 + nn;
        const int n = nt * 16 + (lane & 15);
        const int k = kt * 32 + (lane >> 4) * 8 + j;
        float v = 0.f;
        if (n < HH) {
            if (k < HH)       v = W2[n * HH + k];
            else if (k == HH) v = b2[n];
        }
        w2b[i] = (_Float16)v;
    }
}

// fc1 on MFMA: gather x rows -> fp16 A-frags in LDS; P = u*W1a^T + b1 (kt 0..3),
// Q = v*W1b^T (kt 4..7). Epilogue transposes through LDS for coalesced stores.
__global__ __launch_bounds__(256, 2)
void fc1_kernel(const float* __restrict__ x, const int* __restrict__ ind,
                char* __restrict__ ws)
{
    const _Float16* w1b = (const _Float16*)(ws + OFF_W1B);
    const float* b1p    = (const float*)(ws + OFF_B1P);
    const int i0 = blockIdx.x * 128;

    __shared__ __align__(16) char lds[65536];   // At [8 kt][8 mt][64 slot][8] f16
    _Float16* At  = (_Float16*)lds;
    _Float16* buf = (_Float16*)lds;

    const int t    = threadIdx.x;
    const int lane = t & 63, w = t >> 6;
    const int tx   = lane & 15, quad = lane >> 4;
    const int colw = w * 80;

    {
        const int m = t >> 1, c = t & 1;
        const int mt = m >> 4, ml = m & 15;
        const int r = ind[i0 + m];
        const float* xr = x + (size_t)r * DD;
        #pragma unroll
        for (int i = 0; i < 16; ++i) {
            const int ch = 2 * i + c;
            const int kt = ch >> 2, qd = ch & 3;
            const float4 f0 = *(const float4*)(xr + ch * 8);
            const float4 f1 = *(const float4*)(xr + ch * 8 + 4);
            f16x8 h;
            h[0] = (_Float16)f0.x; h[1] = (_Float16)f0.y;
            h[2] = (_Float16)f0.z; h[3] = (_Float16)f0.w;
            h[4] = (_Float16)f1.x; h[5] = (_Float16)f1.y;
            h[6] = (_Float16)f1.z; h[7] = (_Float16)f1.w;
            *(f16x8*)(At + ((size_t)(kt * 8 + mt) * 64 + ml * 4 + qd) * 8) = h;
        }
    }
    __syncthreads();

    #pragma unroll
    for (int ph = 0; ph < 2; ++ph) {
        fx4 acc[8][5] = {};
        #pragma unroll
        for (int kt = 0; kt < 4; ++kt) {
            const int ktg = ph * 4 + kt;
            f16x8 bf[5];
            #pragma unroll
            for (int n = 0; n < 5; ++n)
                bf[n] = *(const f16x8*)(w1b + ((size_t)((w * 5 + n) * 8 + ktg) * 64 + lane) * 8);
            #pragma unroll
            for (int mh = 0; mh < 2; ++mh) {
                f16x8 af[4];
                #pragma unroll
                for (int mi = 0; mi < 4; ++mi)
                    af[mi] = *(const f16x8*)(At + ((size_t)(ktg * 8 + mh * 4 + mi) * 64 + tx * 4 + quad) * 8);
                #pragma unroll
                for (int mi = 0; mi < 4; ++mi)
                    #pragma unroll
                    for (int n = 0; n < 5; ++n)
                        acc[mh * 4 + mi][n] =
                            __builtin_amdgcn_mfma_f32_16x16x32_f16(af[mi], bf[n], acc[mh * 4 + mi][n], 0, 0, 0);
            }
        }
        _Float16* out = (_Float16*)(ws + (ph ? OFF_Q : OFF_P));
        #pragma unroll
        for (int g = 0; g < 4; ++g) {
            __syncthreads();
            #pragma unroll
            for (int mi = 0; mi < 2; ++mi) {
                const int mt = g * 2 + mi;
                #pragma unroll
                for (int n = 0; n < 5; ++n) {
                    const int col = colw + n * 16 + tx;
                    const float bb = (ph == 0) ? b1p[col] : 0.f;
                    #pragma unroll
                    for (int r = 0; r < 4; ++r) {
                        const int row32 = mi * 16 + quad * 4 + r;
                        buf[row32 * 328 + col] = (_Float16)(acc[mt][n][r] + bb);
                    }
                }
            }
            __syncthreads();
            #pragma unroll
            for (int s5 = 0; s5 < 5; ++s5) {
                const int idx = t + s5 * 256;
                const int rr = idx / 40, cc = idx - rr * 40;
                *(uint4*)(out + (size_t)(i0 + g * 32 + rr) * PSTRIDE + cc * 8) =
                    *(const uint4*)(buf + rr * 328 + cc * 8);
            }
        }
        __syncthreads();
    }
}

// fc2+fc3: h1 = relu(P_i + Q_{(i+shift)&mask}) [col 300 = 1 -> b2 fold];
// h2 = h1*W2b^T; epilogue in exp2/log2 domain.
// R10: grid (1024, 21); 512 threads / 8 waves as (mh 0..1) x (nq 0..3);
// each wave = R7 shape: 64 rows (mt = mh*4+mi) x 80-col quadrant, acc[4][5].
// At slots XOR-swizzled; w2b streamed kt-major; setprio around MFMA cluster;
// part aliases At after the post-MFMA barrier.
__global__ __launch_bounds__(512, 2)
void fc23_kernel(char* __restrict__ ws)
{
    const _Float16* w2b = (const _Float16*)(ws + OFF_W2B);
    const float* w3p = (const float*)(ws + OFF_W3P);
    const float* c2p = (const float*)(ws + OFF_C2);
    const _Float16* P = (const _Float16*)(ws + OFF_P);
    const _Float16* Q = (const _Float16*)(ws + OFF_Q);
    double* S = (double*)(ws + OFF_S);

    const int p  = blockIdx.y;
    const int i0 = blockIdx.x * 128;
    const unsigned shift = (p == 0) ? 0u : (((unsigned)p * 2654435761u) & NMASK);

    __shared__ __align__(16) char lds[81920];
    _Float16* At = (_Float16*)lds;              // [8 mt][10 kt][64 slot^swz][8] f16
    float* part = (float*)lds;                  // [128 rows][4 nq], aliases At

    const int t    = threadIdx.x;
    const int lane = t & 63, w = t >> 6;        // w = (mh<<2)|nq, 0..7
    const int tx   = lane & 15, quad = lane >> 4;
    const int mh   = w >> 2, nq = w & 3;
    const int colw = nq * 80;

    // B-frag stream base (kt-major): frag (kt,n) at +(kt*5+n)*512 f16
    const _Float16* wb = w2b + (size_t)(nq * 50) * 512 + (size_t)lane * 8;
    f16x8 bA[5], bB[5];
    #pragma unroll
    for (int n = 0; n < 5; ++n) bA[n] = *(const f16x8*)(wb + (size_t)n * 512);

    { // stage h1 = relu(P+Q): 4 threads/row over 128 rows, 10 chunks each
        const int c = t & 3, m = t >> 2;                     // m = 0..127
        const int mt = m >> 4, ml = m & 15;
        const int prow = i0 + m;
        int ws_ = ml * 4 + c;  ws_ ^= (ws_ >> 3) & 3;        // swizzled write slot
        const _Float16* pr = P + (size_t)prow * PSTRIDE;
        const _Float16* qr = Q + (size_t)(((unsigned)prow + shift) & NMASK) * PSTRIDE;
        #pragma unroll
        for (int i = 0; i < 10; ++i) {
            const int ch = c + 4 * i;                        // kt = i, cq = c
            f16x8 hp = *(const f16x8*)(pr + ch * 8);
            f16x8 hq = *(const f16x8*)(qr + ch * 8);
            f16x8 sv = hp + hq;
            sv = __builtin_elementwise_max(sv, (f16x8)(_Float16)0);
            if (i == 9 && c == 1) sv[4] = (_Float16)1.f;     // ch=37, k=300: bias col
            *(f16x8*)(At + ((size_t)(mt * 10 + i) * 64 + ws_) * 8) = sv;
        }
    }
    __syncthreads();

    int rs = tx * 4 + quad;  rs ^= (rs >> 3) & 3;            // swizzled read slot

    fx4 acc[4][5] = {};
    #pragma unroll
    for (int kt = 0; kt < 10; ++kt) {
        f16x8* bc = (kt & 1) ? bB : bA;
        f16x8* bn = (kt & 1) ? bA : bB;
        if (kt < 9) {
            #pragma unroll
            for (int n = 0; n < 5; ++n)
                bn[n] = *(const f16x8*)(wb + (size_t)((kt + 1) * 5 + n) * 512);
        }
        f16x8 af[4];
        #pragma unroll
        for (int mi = 0; mi < 4; ++mi)
            af[mi] = *(const f16x8*)(At + ((size_t)((mh * 4 + mi) * 10 + kt) * 64 + rs) * 8);
        __builtin_amdgcn_s_setprio(1);
        #pragma unroll
        for (int mi = 0; mi < 4; ++mi)
            #pragma unroll
            for (int n = 0; n < 5; ++n)
                acc[mi][n] =
                    __builtin_amdgcn_mfma_f32_16x16x32_f16(af[mi], bc[n], acc[mi][n], 0, 0, 0);
        __builtin_amdgcn_s_setprio(0);
    }

    // epilogue: fc3 dot (p==0) or marginalized-dropout product (p>0),
    // in exp2/log2 domain; results held in regs until the part exchange
    float w3v[5], c2v[5];
    #pragma unroll
    for (int n = 0; n < 5; ++n) {
        w3v[n] = w3p[colw + n * 16 + tx];
        c2v[n] = c2p[colw + n * 16 + tx];
    }
    float psv[4][4];
    #pragma unroll
    for (int mi = 0; mi < 4; ++mi) {
        float ps[4];
        if (p == 0) {
            ps[0] = ps[1] = ps[2] = ps[3] = 0.f;
            #pragma unroll
            for (int n = 0; n < 5; ++n)
                #pragma unroll
                for (int r = 0; r < 4; ++r)
                    ps[r] = fmaf(w3v[n], fmaxf(acc[mi][n][r], 0.f), ps[r]);
        } else {
            float prd[4] = {1.f, 1.f, 1.f, 1.f};
            #pragma unroll
            for (int n = 0; n < 5; ++n)
                #pragma unroll
                for (int r = 0; r < 4; ++r) {
                    const float hr = fmaxf(acc[mi][n][r], 0.f);
                    const float u  = __builtin_amdgcn_exp2f(c2v[n] * hr);  // e^{2a}
                    prd[r] *= fmaf(0.5f, u, 0.5f);
                }
            #pragma unroll
            for (int r = 0; r < 4; ++r)
                ps[r] = __builtin_amdgcn_logf(prd[r]);   // v_log_f32 = log2
        }
        #pragma unroll
        for (int r = 0; r < 4; ++r) {
            float v = ps[r];
            v += __shfl_xor(v, 1); v += __shfl_xor(v, 2);
            v += __shfl_xor(v, 4); v += __shfl_xor(v, 8);
            psv[mi][r] = v;
        }
    }
    __syncthreads();   // all At reads done -> part may alias At

    if (tx == 0) {
        #pragma unroll
        for (int mi = 0; mi < 4; ++mi)
            #pragma unroll
            for (int r = 0; r < 4; ++r)
                part[((mh * 4 + mi) * 16 + quad * 4 + r) * 4 + nq] = psv[mi][r];
    }
    __syncthreads();

    if (t < 128) {     // waves 0-1: fold 4 nq partials, reduce 128 rows
        const float4 pv = *(const float4*)(part + t * 4);
        const float s = pv.x + pv.y + pv.z + pv.w;
        float tot = (p == 0) ? s : __builtin_amdgcn_exp2f(s);
        tot += __shfl_xor(tot, 1);  tot += __shfl_xor(tot, 2);
        tot += __shfl_xor(tot, 4);  tot += __shfl_xor(tot, 8);
        tot += __shfl_xor(tot, 16); tot += __shfl_xor(tot, 32);
        if ((t & 63) == 0) atomicAdd(&S[p], (double)tot);
    }
}

__global__ void fin_kernel(char* __restrict__ ws, float* __restrict__ out)
{
    if (threadIdx.x == 0 && blockIdx.x == 0) {
        const double* S = (const double*)(ws + OFF_S);
        double m1 = S[0] / (double)N_SAMP;
        double a = 0.0;
        for (int p = 1; p <= KPASS; ++p) a += log(S[p] / (double)N_SAMP);
        out[0] = (float)(m1 - a / (double)KPASS);
    }
}

extern "C" void kernel_launch(void* const* d_in, const int* in_sizes, int n_in,
                              void* d_out, int out_size, void* d_ws, size_t ws_size,
                              hipStream_t stream)
{
    const float* x  = (const float*)d_in[0];
    const int* ind  = (const int*)d_in[1];
    const float* W1 = (const float*)d_in[2];
    const float* b1 = (const float*)d_in[3];
    const float* W2 = (const float*)d_in[4];
    const float* b2 = (const float*)d_in[5];
    const float* W3 = (const float*)d_in[6];
    char* ws = (char*)d_ws;

    hipLaunchKernelGGL(prep_kernel, dim3(512), dim3(256), 0, stream, W1, b1, W2, b2, W3, ws);
    hipLaunchKernelGGL(fc1_kernel, dim3(N_SAMP / 128), dim3(256), 0, stream, x, ind, ws);
    hipLaunchKernelGGL(fc23_kernel, dim3(N_SAMP / 128, KPASS + 1), dim3(512), 0, stream, ws);
    hipLaunchKernelGGL(fin_kernel, dim3(1), dim3(64), 0, stream, ws, (float*)d_out);
}